// Round 10
// baseline (485.149 us; speedup 1.0000x reference)
//
#include <hip/hip_runtime.h>
#include <hip/hip_fp16.h>
#include <math.h>

// ---------------------------------------------------------------------------
// GraphNet: 3x EdgeConv (fully linearized) + GAT(2 heads, concat=False)
//
// out[d] = relu( (Σ_{e→d} h[src_e]) @ W1 + B5[d] @ W2 + deg[d]·c )
//
// R16 post-mortem: 8-deep ladder cut gat_agg 116.6->78.1 (MLP theory OK),
//   but 78us at 0.85 TB/s effective = NOT fabric-bound (EC gathers run 2.3).
//   VALU 46%, occ 40% -> serial LATENCY CHAIN: csr->asrc(random 8B)->logit->
//   ~30-op softmax shfl chain -> only then h3 loads issue, though their
//   addresses were known at chunk start.
// R17: hoist the h3 load ladder ABOVE the softmax. Per chunk: issue asrc +
//   batch-1 (8 edges) h3 loads first (padding lanes -> row 0, w=0, L1-hot),
//   softmax overlaps the in-flight loads, batch-2 issues before batch-1 fma.
//   Same accumulation order -> bit-identical result.
// R15 (stone): gather time ∝ in-flight lines, not bytes; keep >=8 lines.
// R14 (stone): launch gaps ~0; dispatch count irrelevant.
// R12 (stone): 2 weight streams from global thrash L1 -> stage one in LDS.
// R11 (stone): per-edge LDS atomics poison; src-sort no help.
// Precision: x,h fp16 storage / fp32 accum; Wg fp16; agg staged fp16.
// ---------------------------------------------------------------------------

#define TPB 256

typedef unsigned int u32;

__device__ inline float2 f16unpack2(u32 u) {
    __half2 h = *reinterpret_cast<__half2*>(&u);
    return __half22float2(h);
}
__device__ inline float4 f16unpack4(uint2 q) {
    float2 a = f16unpack2(q.x), b = f16unpack2(q.y);
    return make_float4(a.x, a.y, b.x, b.y);
}
__device__ inline u32 f16pack2(float lo, float hi) {
    __half2 h = __floats2half2_rn(lo, hi);
    return *reinterpret_cast<u32*>(&h);
}
__device__ inline void acc_h16(float4& acc, uint2 v) {
    float2 a = f16unpack2(v.x);
    float2 b = f16unpack2(v.y);
    acc.x += a.x; acc.y += a.y; acc.z += b.x; acc.w += b.y;
}

#define MAC4(acc, a, w0, w1, w2, w3)                                           \
    acc.x = fmaf(a.x, w0.x, acc.x); acc.y = fmaf(a.x, w0.y, acc.y);            \
    acc.z = fmaf(a.x, w0.z, acc.z); acc.w = fmaf(a.x, w0.w, acc.w);            \
    acc.x = fmaf(a.y, w1.x, acc.x); acc.y = fmaf(a.y, w1.y, acc.y);            \
    acc.z = fmaf(a.y, w1.z, acc.z); acc.w = fmaf(a.y, w1.w, acc.w);            \
    acc.x = fmaf(a.z, w2.x, acc.x); acc.y = fmaf(a.z, w2.y, acc.y);            \
    acc.z = fmaf(a.z, w2.z, acc.z); acc.w = fmaf(a.z, w2.w, acc.w);            \
    acc.x = fmaf(a.w, w3.x, acc.x); acc.y = fmaf(a.w, w3.y, acc.y);            \
    acc.z = fmaf(a.w, w3.z, acc.z); acc.w = fmaf(a.w, w3.w, acc.w);

// ------- mega-prep: folds + Wg fp16 pack + vsd fold + x cvt + rs zero -------
struct CombPtrs {
    const float* wn; const float* bn;
    const float* we; const float* be;
    const float* wc; const float* bc;
    float* W1;   // W1(4096) | W2(320) | cv(64)
};

__global__ __launch_bounds__(TPB) void k_prep(CombPtrs p0, CombPtrs p1, CombPtrs p2,
                                              const float* __restrict__ wg, u32* __restrict__ wgh,
                                              const float* __restrict__ att_src,
                                              const float* __restrict__ att_dst,
                                              float* __restrict__ vsd,      // [4][64]: s_h0|s_h1|d_h0|d_h1
                                              const float4* __restrict__ X, uint4* __restrict__ XH,
                                              int n8, int nbC,
                                              int* __restrict__ rs, int nz) {
    const int b = blockIdx.x;
    if (b >= 4 + nbC) {
        int i = (b - 4 - nbC) * TPB + threadIdx.x;
        if (i < nz) rs[i] = 0;
        return;
    }
    if (b >= 4) {
        int i = (b - 4) * TPB + threadIdx.x;
        if (i < n8) {
            float4 a = X[i * 2], c = X[i * 2 + 1];
            uint4 o;
            o.x = f16pack2(a.x, a.y); o.y = f16pack2(a.z, a.w);
            o.z = f16pack2(c.x, c.y); o.w = f16pack2(c.z, c.w);
            XH[i] = o;
        }
        return;
    }
    if (b == 3) {
        // pack Wg [64][128] fp32 -> [64][64] u32 (half2 pairs)
        for (int i = threadIdx.x; i < 4096; i += TPB) {
            float2 v = *(const float2*)&wg[i * 2];
            wgh[i] = f16pack2(v.x, v.y);
        }
        // fold score vectors: vsd[type][k] = Σ_c Wg[k, h*64+c] * att[h][c]
        {
            int i = threadIdx.x;   // 256 threads, one dot each
            int type = i >> 6, k = i & 63;
            int h = type & 1, sd = type >> 1;
            const float* att = (sd ? att_dst : att_src) + h * 64;
            const float* wrow = wg + k * 128 + h * 64;
            float acc = 0.f;
            #pragma unroll 8
            for (int c = 0; c < 64; c++) acc = fmaf(wrow[c], att[c], acc);
            vsd[type * 64 + k] = acc;
        }
        return;
    }
    CombPtrs P = (b == 0) ? p0 : ((b == 1) ? p1 : p2);
    const float* wn = P.wn; const float* bn = P.bn;
    const float* we = P.we; const float* be = P.be;
    const float* wc = P.wc; const float* bc = P.bc;
    float* W1 = P.W1;
    float* W2 = P.W1 + 4096;
    float* cv = P.W1 + 4416;
    int tid = threadIdx.x;
    for (int idx = tid; idx < 64 * 64; idx += TPB) {
        int i = idx >> 6, j = idx & 63;
        float acc = 0.f;
        #pragma unroll 8
        for (int k = 0; k < 64; k++) acc = fmaf(wn[i * 64 + k], wc[k * 64 + j], acc);
        W1[idx] = acc;
    }
    for (int idx = tid; idx < 5 * 64; idx += TPB) {
        int i = idx >> 6, j = idx & 63;
        float acc = 0.f;
        #pragma unroll 8
        for (int k = 0; k < 64; k++) acc = fmaf(we[i * 64 + k], wc[(64 + k) * 64 + j], acc);
        W2[idx] = acc;
    }
    for (int j = tid; j < 64; j += TPB) {
        float acc = bc[j];
        for (int k = 0; k < 64; k++) {
            acc = fmaf(bn[k], wc[k * 64 + j], acc);
            acc = fmaf(be[k], wc[(64 + k) * 64 + j], acc);
        }
        cv[j] = acc;
    }
}

// ---- k_hist: degree histogram + edge rank (atomicAdd return) ---------------
__global__ __launch_bounds__(TPB) void k_hist(const int* __restrict__ dst, int* __restrict__ cnt,
                                              int* __restrict__ rank, int E) {
    int e = blockIdx.x * TPB + threadIdx.x;
    if (e < E) rank[e] = atomicAdd(&cnt[dst[e]], 1);
}

// ---------------- scan (exclusive; scan1 + self-service scan3) --------------
__global__ __launch_bounds__(TPB) void k_scan1(int* __restrict__ data, int* __restrict__ partials, int n) {
    __shared__ int s[TPB];
    int i = blockIdx.x * TPB + threadIdx.x;
    int v = (i < n) ? data[i] : 0;
    s[threadIdx.x] = v;
    __syncthreads();
    for (int off = 1; off < TPB; off <<= 1) {
        int t = (threadIdx.x >= off) ? s[threadIdx.x - off] : 0;
        __syncthreads();
        s[threadIdx.x] += t;
        __syncthreads();
    }
    if (i < n) data[i] = s[threadIdx.x] - v;  // exclusive
    if (threadIdx.x == TPB - 1) partials[blockIdx.x] = s[TPB - 1];
}

// each block sums partials[0..bid) itself (<=400 ints, L2-hit) — no scan2
__global__ __launch_bounds__(TPB) void k_scan3(int* __restrict__ data, const int* __restrict__ partials,
                                               int n, int total) {
    const int bid = blockIdx.x;
    int s = 0;
    for (int j = threadIdx.x; j < bid; j += TPB) s += partials[j];
    #pragma unroll
    for (int off = 32; off > 0; off >>= 1) s += __shfl_down(s, off);
    __shared__ int ws[4];
    if ((threadIdx.x & 63) == 0) ws[threadIdx.x >> 6] = s;
    __syncthreads();
    int pre = ws[0] + ws[1] + ws[2] + ws[3];
    int i = bid * TPB + threadIdx.x;
    if (i < n) data[i] += pre;
    if (i == 0) data[n] = total;
}

// ---- atomic-free scatter: one combined int2{src,e} random 8B stream --------
__global__ __launch_bounds__(TPB) void k_scatter(const int* __restrict__ src, const int* __restrict__ dst,
                                                 const int* __restrict__ rank, const int* __restrict__ row_start,
                                                 int2* __restrict__ csr_se, int E) {
    int e = blockIdx.x * TPB + threadIdx.x;
    if (e < E) {
        int idx = row_start[dst[e]] + rank[e];
        csr_se[idx] = make_int2(src[e], e);
    }
}

// ---- fused EC layer: group-gather into LDS A-tile, then tiled GEMM ---------
// IN16: H rows are 64 halves (128 B); else 64 floats (256 B).
// OUT16: result stored fp16 (one rounding; accumulation fp32).
// SCORES: epilogue computes a_src/a_dst = r4 · vsd[type] + shfl reduce.
// B5C: compute B5 = Σ ea during the gather (lane-own-edge + shfl reduce).
template <bool IN16, bool OUT16, bool SCORES, bool B5C>
__global__ __launch_bounds__(TPB, 6) void k_ec_fused(const void* __restrict__ Hv,
                                                     const int* __restrict__ row_start,
                                                     const int2* __restrict__ csr_se,
                                                     const float* __restrict__ Wfold,  // W1(4096)|W2(320)|cv(64)
                                                     float* __restrict__ B5,
                                                     const float* __restrict__ EA,
                                                     void* __restrict__ OUTv, int n,
                                                     const float* __restrict__ vsd,    // [4][64] (SCORES)
                                                     float* __restrict__ asrc,
                                                     float* __restrict__ adst) {
    __shared__ float Alds[64 * 68];
    __shared__ float Blds[B5C ? 320 : 4];
    const float* Hf = (const float*)Hv;
    const u32*   Hh = (const u32*)Hv;     // [N][32] u32 = [N][64] half
    const int t = threadIdx.x;
    const int base = blockIdx.x * 64;

    // gather phase: 16 lane-groups, 4 rows each, 8-deep load ladder
    const int lane = t & 63;
    const int lid = lane & 15;
    const int gbase = lane & 48;
    const int gid = t >> 4;
    const int c4 = lid * 4;          // float col for this lane
    const int h2i = lid * 2;         // u32 index into fp16 row
    for (int i = 0; i < 4; i++) {
        int r = gid * 4 + i;
        int node = base + r;
        float4 acc = make_float4(0.f, 0.f, 0.f, 0.f);
        float b0 = 0.f, b1 = 0.f, b2 = 0.f, b3 = 0.f, b4 = 0.f;
        if (node < n) {
            int beg = row_start[node], end = row_start[node + 1];
            for (int chunk = beg; chunk < end; chunk += 16) {
                int cdeg = min(end - chunk, 16);
                bool ev = (chunk + lid < end);
                int2 se = ev ? csr_se[chunk + lid] : make_int2(0, 0);
                int s_l = se.x;
                if (B5C && ev) {
                    const float* p = EA + (size_t)se.y * 5;
                    b0 += p[0]; b1 += p[1]; b2 += p[2]; b3 += p[3]; b4 += p[4];
                }
                int it = 0;
                for (; it + 7 < cdeg; it += 8) {
                    int se0 = __shfl(s_l, gbase + it);
                    int se1 = __shfl(s_l, gbase + it + 1);
                    int se2 = __shfl(s_l, gbase + it + 2);
                    int se3 = __shfl(s_l, gbase + it + 3);
                    int se4 = __shfl(s_l, gbase + it + 4);
                    int se5 = __shfl(s_l, gbase + it + 5);
                    int se6 = __shfl(s_l, gbase + it + 6);
                    int se7 = __shfl(s_l, gbase + it + 7);
                    if (IN16) {
                        uint2 v0 = *(const uint2*)&Hh[(size_t)se0 * 32 + h2i];
                        uint2 v1 = *(const uint2*)&Hh[(size_t)se1 * 32 + h2i];
                        uint2 v2 = *(const uint2*)&Hh[(size_t)se2 * 32 + h2i];
                        uint2 v3 = *(const uint2*)&Hh[(size_t)se3 * 32 + h2i];
                        uint2 v4 = *(const uint2*)&Hh[(size_t)se4 * 32 + h2i];
                        uint2 v5 = *(const uint2*)&Hh[(size_t)se5 * 32 + h2i];
                        uint2 v6 = *(const uint2*)&Hh[(size_t)se6 * 32 + h2i];
                        uint2 v7 = *(const uint2*)&Hh[(size_t)se7 * 32 + h2i];
                        acc_h16(acc, v0); acc_h16(acc, v1); acc_h16(acc, v2); acc_h16(acc, v3);
                        acc_h16(acc, v4); acc_h16(acc, v5); acc_h16(acc, v6); acc_h16(acc, v7);
                    } else {
                        float4 v0 = *(const float4*)&Hf[(size_t)se0 * 64 + c4];
                        float4 v1 = *(const float4*)&Hf[(size_t)se1 * 64 + c4];
                        float4 v2 = *(const float4*)&Hf[(size_t)se2 * 64 + c4];
                        float4 v3 = *(const float4*)&Hf[(size_t)se3 * 64 + c4];
                        float4 v4 = *(const float4*)&Hf[(size_t)se4 * 64 + c4];
                        float4 v5 = *(const float4*)&Hf[(size_t)se5 * 64 + c4];
                        float4 v6 = *(const float4*)&Hf[(size_t)se6 * 64 + c4];
                        float4 v7 = *(const float4*)&Hf[(size_t)se7 * 64 + c4];
                        acc.x += ((v0.x + v1.x) + (v2.x + v3.x)) + ((v4.x + v5.x) + (v6.x + v7.x));
                        acc.y += ((v0.y + v1.y) + (v2.y + v3.y)) + ((v4.y + v5.y) + (v6.y + v7.y));
                        acc.z += ((v0.z + v1.z) + (v2.z + v3.z)) + ((v4.z + v5.z) + (v6.z + v7.z));
                        acc.w += ((v0.w + v1.w) + (v2.w + v3.w)) + ((v4.w + v5.w) + (v6.w + v7.w));
                    }
                }
                for (; it + 3 < cdeg; it += 4) {
                    int se0 = __shfl(s_l, gbase + it);
                    int se1 = __shfl(s_l, gbase + it + 1);
                    int se2 = __shfl(s_l, gbase + it + 2);
                    int se3 = __shfl(s_l, gbase + it + 3);
                    if (IN16) {
                        uint2 v0 = *(const uint2*)&Hh[(size_t)se0 * 32 + h2i];
                        uint2 v1 = *(const uint2*)&Hh[(size_t)se1 * 32 + h2i];
                        uint2 v2 = *(const uint2*)&Hh[(size_t)se2 * 32 + h2i];
                        uint2 v3 = *(const uint2*)&Hh[(size_t)se3 * 32 + h2i];
                        acc_h16(acc, v0); acc_h16(acc, v1); acc_h16(acc, v2); acc_h16(acc, v3);
                    } else {
                        float4 v0 = *(const float4*)&Hf[(size_t)se0 * 64 + c4];
                        float4 v1 = *(const float4*)&Hf[(size_t)se1 * 64 + c4];
                        float4 v2 = *(const float4*)&Hf[(size_t)se2 * 64 + c4];
                        float4 v3 = *(const float4*)&Hf[(size_t)se3 * 64 + c4];
                        acc.x += (v0.x + v1.x) + (v2.x + v3.x);
                        acc.y += (v0.y + v1.y) + (v2.y + v3.y);
                        acc.z += (v0.z + v1.z) + (v2.z + v3.z);
                        acc.w += (v0.w + v1.w) + (v2.w + v3.w);
                    }
                }
                for (; it < cdeg; it++) {
                    int se_ = __shfl(s_l, gbase + it);
                    if (IN16) {
                        uint2 v = *(const uint2*)&Hh[(size_t)se_ * 32 + h2i];
                        acc_h16(acc, v);
                    } else {
                        float4 v = *(const float4*)&Hf[(size_t)se_ * 64 + c4];
                        acc.x += v.x; acc.y += v.y; acc.z += v.z; acc.w += v.w;
                    }
                }
            }
        }
        *(float4*)&Alds[r * 68 + c4] = acc;
        if (B5C) {
            #pragma unroll
            for (int off = 1; off < 16; off <<= 1) {
                b0 += __shfl_xor(b0, off); b1 += __shfl_xor(b1, off);
                b2 += __shfl_xor(b2, off); b3 += __shfl_xor(b3, off);
                b4 += __shfl_xor(b4, off);
            }
            if (lid == 0 && node < n) {
                Blds[r * 5 + 0] = b0; Blds[r * 5 + 1] = b1; Blds[r * 5 + 2] = b2;
                Blds[r * 5 + 3] = b3; Blds[r * 5 + 4] = b4;
                float* bp = B5 + (size_t)node * 5;
                bp[0] = b0; bp[1] = b1; bp[2] = b2; bp[3] = b3; bp[4] = b4;
            }
        }
    }
    __syncthreads();

    // GEMM phase — A from LDS, Wfold straight from global (L1 broadcast)
    const int r0 = (t >> 4) * 4, c0 = (t & 15) * 4;
    float4 acc0 = make_float4(0.f, 0.f, 0.f, 0.f), acc1 = acc0, acc2 = acc0, acc3 = acc0;
    #pragma unroll 2
    for (int k = 0; k < 64; k += 4) {
        float4 a0 = *(float4*)&Alds[(r0 + 0) * 68 + k];
        float4 a1 = *(float4*)&Alds[(r0 + 1) * 68 + k];
        float4 a2 = *(float4*)&Alds[(r0 + 2) * 68 + k];
        float4 a3 = *(float4*)&Alds[(r0 + 3) * 68 + k];
        float4 w0 = *(const float4*)&Wfold[(k + 0) * 64 + c0];
        float4 w1 = *(const float4*)&Wfold[(k + 1) * 64 + c0];
        float4 w2 = *(const float4*)&Wfold[(k + 2) * 64 + c0];
        float4 w3 = *(const float4*)&Wfold[(k + 3) * 64 + c0];
        MAC4(acc0, a0, w0, w1, w2, w3);
        MAC4(acc1, a1, w0, w1, w2, w3);
        MAC4(acc2, a2, w0, w1, w2, w3);
        MAC4(acc3, a3, w0, w1, w2, w3);
    }
    float4 w2c[5];
    #pragma unroll
    for (int j = 0; j < 5; j++) w2c[j] = *(const float4*)&Wfold[4096 + j * 64 + c0];
    const float4 cv4 = *(const float4*)&Wfold[4416 + c0];
    float4 vs0, vs1, vd0, vd1;
    if (SCORES) {
        vs0 = *(const float4*)&vsd[0 * 64 + c0];
        vs1 = *(const float4*)&vsd[1 * 64 + c0];
        vd0 = *(const float4*)&vsd[2 * 64 + c0];
        vd1 = *(const float4*)&vsd[3 * 64 + c0];
    }

    #define DOT4(a, b) (a.x * b.x + a.y * b.y + a.z * b.z + a.w * b.w)
    #define EC_STORE(i, acc)                                                        \
        { int row = base + r0 + i;                                                  \
          if (row < n) {                                                            \
              float deg = (float)(row_start[row + 1] - row_start[row]);             \
              float4 q;                                                             \
              q.x = deg * cv4.x; q.y = deg * cv4.y;                                 \
              q.z = deg * cv4.z; q.w = deg * cv4.w;                                 \
              for (int j = 0; j < 5; j++) {                                         \
                  float b = B5C ? Blds[(r0 + i) * 5 + j] : B5[(size_t)row * 5 + j]; \
                  q.x = fmaf(b, w2c[j].x, q.x); q.y = fmaf(b, w2c[j].y, q.y);       \
                  q.z = fmaf(b, w2c[j].z, q.z); q.w = fmaf(b, w2c[j].w, q.w);       \
              }                                                                     \
              float4 r4;                                                            \
              r4.x = fmaxf(acc.x + q.x, 0.f); r4.y = fmaxf(acc.y + q.y, 0.f);       \
              r4.z = fmaxf(acc.z + q.z, 0.f); r4.w = fmaxf(acc.w + q.w, 0.f);       \
              if (SCORES) {                                                         \
                  float s0 = DOT4(r4, vs0), s1 = DOT4(r4, vs1);                     \
                  float d0 = DOT4(r4, vd0), d1 = DOT4(r4, vd1);                     \
                  s0 += __shfl_xor(s0, 1); s1 += __shfl_xor(s1, 1);                 \
                  d0 += __shfl_xor(d0, 1); d1 += __shfl_xor(d1, 1);                 \
                  s0 += __shfl_xor(s0, 2); s1 += __shfl_xor(s1, 2);                 \
                  d0 += __shfl_xor(d0, 2); d1 += __shfl_xor(d1, 2);                 \
                  s0 += __shfl_xor(s0, 4); s1 += __shfl_xor(s1, 4);                 \
                  d0 += __shfl_xor(d0, 4); d1 += __shfl_xor(d1, 4);                 \
                  s0 += __shfl_xor(s0, 8); s1 += __shfl_xor(s1, 8);                 \
                  d0 += __shfl_xor(d0, 8); d1 += __shfl_xor(d1, 8);                 \
                  if ((t & 15) == 0) {                                              \
                      float2 sv; sv.x = s0; sv.y = s1;                              \
                      float2 dv; dv.x = d0; dv.y = d1;                              \
                      *(float2*)&asrc[(size_t)row * 2] = sv;                        \
                      *(float2*)&adst[(size_t)row * 2] = dv;                        \
                  }                                                                 \
              }                                                                     \
              if (OUT16) {                                                          \
                  u32* O = (u32*)OUTv;                                              \
                  uint2 gg;                                                         \
                  gg.x = f16pack2(r4.x, r4.y); gg.y = f16pack2(r4.z, r4.w);         \
                  *(uint2*)&O[(size_t)row * 32 + (c0 >> 1)] = gg;                   \
              } else {                                                              \
                  float* O = (float*)OUTv;                                          \
                  *(float4*)&O[(size_t)row * 64 + c0] = r4;                         \
              } } }
    EC_STORE(0, acc0) EC_STORE(1, acc1) EC_STORE(2, acc2) EC_STORE(3, acc3)
    #undef EC_STORE
    #undef DOT4
}

// ----- GAT aggregation, h3-space, 64 nodes/block, latency-pipelined:
//   per chunk: csr+asrc loads -> batch-1 h3 ladder ISSUES -> softmax chain
//   (overlaps loads) -> batch-2 issues -> fma (same order = bit-identical).
//   Padding lanes: s_l=0 -> row 0 (L1-hot), weight 0.
__global__ __launch_bounds__(TPB, 6) void k_gat_agg(const u32* __restrict__ Hh,     // h3 fp16 [N][32] u32
                                                    const int* __restrict__ row_start,
                                                    const int2* __restrict__ csr_se,
                                                    const float* __restrict__ asrc,
                                                    const float* __restrict__ adst,
                                                    const u32* __restrict__ Wgh,    // [64][64] u32 fp16
                                                    const float* __restrict__ bgat,
                                                    float* __restrict__ OUT, int n) {
    __shared__ u32 Ash[64 * 66];   // node r: [r*66 + 0..31]=head0 dim-pairs, [+32..63]=head1
    const int t = threadIdx.x;
    const int base = blockIdx.x * 64;
    const int lane = t & 63;
    const int lid = lane & 15;
    const int gbase = lane & 48;
    const int gid = t >> 4;
    const int h2i = lid * 2;

    #define EDGE_FMA(hv, wa0, wa1)                                              \
        { float4 hx = f16unpack4(hv);                                           \
          A0[0] = fmaf(wa0, hx.x, A0[0]); A1[0] = fmaf(wa1, hx.x, A1[0]);       \
          A0[1] = fmaf(wa0, hx.y, A0[1]); A1[1] = fmaf(wa1, hx.y, A1[1]);       \
          A0[2] = fmaf(wa0, hx.z, A0[2]); A1[2] = fmaf(wa1, hx.z, A1[2]);       \
          A0[3] = fmaf(wa0, hx.w, A0[3]); A1[3] = fmaf(wa1, hx.w, A1[3]); }

    for (int i = 0; i < 4; i++) {
        int r = gid * 4 + i;
        int node = base + r;
        float m0 = -INFINITY, m1 = -INFINITY, d0 = 0.f, d1 = 0.f;
        float A0[4] = {0.f, 0.f, 0.f, 0.f};
        float A1[4] = {0.f, 0.f, 0.f, 0.f};
        if (node < n) {
            int beg = row_start[node], end = row_start[node + 1];
            float2 adv = *(const float2*)&adst[(size_t)node * 2];
            for (int chunk = beg; chunk < end; chunk += 16) {
                int cdeg = min(end - chunk, 16);
                bool valid = (lid < cdeg);
                int s_l = valid ? csr_se[chunk + lid].x : 0;
                // head of critical path: per-lane random asrc read (8B)
                float2 av = *(const float2*)&asrc[(size_t)s_l * 2];
                // broadcast batch-1 source ids and ISSUE their h3 loads now —
                // they fly while the softmax chain below executes.
                int s0i = __shfl(s_l, gbase + 0);
                int s1i = __shfl(s_l, gbase + 1);
                int s2i = __shfl(s_l, gbase + 2);
                int s3i = __shfl(s_l, gbase + 3);
                int s4i = __shfl(s_l, gbase + 4);
                int s5i = __shfl(s_l, gbase + 5);
                int s6i = __shfl(s_l, gbase + 6);
                int s7i = __shfl(s_l, gbase + 7);
                uint2 v0 = *(const uint2*)&Hh[(size_t)s0i * 32 + h2i];
                uint2 v1 = *(const uint2*)&Hh[(size_t)s1i * 32 + h2i];
                uint2 v2 = *(const uint2*)&Hh[(size_t)s2i * 32 + h2i];
                uint2 v3 = *(const uint2*)&Hh[(size_t)s3i * 32 + h2i];
                uint2 v4 = *(const uint2*)&Hh[(size_t)s4i * 32 + h2i];
                uint2 v5 = *(const uint2*)&Hh[(size_t)s5i * 32 + h2i];
                uint2 v6 = *(const uint2*)&Hh[(size_t)s6i * 32 + h2i];
                uint2 v7 = *(const uint2*)&Hh[(size_t)s7i * 32 + h2i];
                // logits + online softmax (overlaps the loads above)
                float al0 = -INFINITY, al1 = -INFINITY;
                if (valid) {
                    float t0 = av.x + adv.x, t1 = av.y + adv.y;
                    al0 = (t0 > 0.f) ? t0 : 0.2f * t0;
                    al1 = (t1 > 0.f) ? t1 : 0.2f * t1;
                }
                float cm0 = al0, cm1 = al1;
                #pragma unroll
                for (int off = 1; off < 16; off <<= 1) {
                    cm0 = fmaxf(cm0, __shfl_xor(cm0, off));
                    cm1 = fmaxf(cm1, __shfl_xor(cm1, off));
                }
                float nm0 = fmaxf(m0, cm0), nm1 = fmaxf(m1, cm1);
                float sc0 = __expf(m0 - nm0), sc1 = __expf(m1 - nm1);  // 0 on first chunk
                float w0 = valid ? __expf(al0 - nm0) : 0.f;
                float w1 = valid ? __expf(al1 - nm1) : 0.f;
                float cd0 = w0, cd1 = w1;
                #pragma unroll
                for (int off = 1; off < 16; off <<= 1) {
                    cd0 += __shfl_xor(cd0, off);
                    cd1 += __shfl_xor(cd1, off);
                }
                d0 = d0 * sc0 + cd0;
                d1 = d1 * sc1 + cd1;
                #pragma unroll
                for (int j = 0; j < 4; j++) { A0[j] *= sc0; A1[j] *= sc1; }
                m0 = nm0; m1 = nm1;
                // batch-2 loads issue BEFORE batch-1 consumption
                bool more = (cdeg > 8);
                uint2 v8, v9, v10, v11, v12, v13, v14, v15;
                if (more) {
                    int s8i  = __shfl(s_l, gbase + 8);
                    int s9i  = __shfl(s_l, gbase + 9);
                    int s10i = __shfl(s_l, gbase + 10);
                    int s11i = __shfl(s_l, gbase + 11);
                    int s12i = __shfl(s_l, gbase + 12);
                    int s13i = __shfl(s_l, gbase + 13);
                    int s14i = __shfl(s_l, gbase + 14);
                    int s15i = __shfl(s_l, gbase + 15);
                    v8  = *(const uint2*)&Hh[(size_t)s8i  * 32 + h2i];
                    v9  = *(const uint2*)&Hh[(size_t)s9i  * 32 + h2i];
                    v10 = *(const uint2*)&Hh[(size_t)s10i * 32 + h2i];
                    v11 = *(const uint2*)&Hh[(size_t)s11i * 32 + h2i];
                    v12 = *(const uint2*)&Hh[(size_t)s12i * 32 + h2i];
                    v13 = *(const uint2*)&Hh[(size_t)s13i * 32 + h2i];
                    v14 = *(const uint2*)&Hh[(size_t)s14i * 32 + h2i];
                    v15 = *(const uint2*)&Hh[(size_t)s15i * 32 + h2i];
                }
                // fma batch 1 (padding edges have w=0 — adds zero)
                {
                    float w00 = __shfl(w0, gbase + 0), w10 = __shfl(w1, gbase + 0);
                    float w01 = __shfl(w0, gbase + 1), w11 = __shfl(w1, gbase + 1);
                    float w02 = __shfl(w0, gbase + 2), w12 = __shfl(w1, gbase + 2);
                    float w03 = __shfl(w0, gbase + 3), w13 = __shfl(w1, gbase + 3);
                    float w04 = __shfl(w0, gbase + 4), w14 = __shfl(w1, gbase + 4);
                    float w05 = __shfl(w0, gbase + 5), w15 = __shfl(w1, gbase + 5);
                    float w06 = __shfl(w0, gbase + 6), w16 = __shfl(w1, gbase + 6);
                    float w07 = __shfl(w0, gbase + 7), w17 = __shfl(w1, gbase + 7);
                    EDGE_FMA(v0, w00, w10) EDGE_FMA(v1, w01, w11)
                    EDGE_FMA(v2, w02, w12) EDGE_FMA(v3, w03, w13)
                    EDGE_FMA(v4, w04, w14) EDGE_FMA(v5, w05, w15)
                    EDGE_FMA(v6, w06, w16) EDGE_FMA(v7, w07, w17)
                }
                if (more) {
                    float w08 = __shfl(w0, gbase + 8),  w18 = __shfl(w1, gbase + 8);
                    float w09 = __shfl(w0, gbase + 9),  w19 = __shfl(w1, gbase + 9);
                    float w0a = __shfl(w0, gbase + 10), w1a = __shfl(w1, gbase + 10);
                    float w0b = __shfl(w0, gbase + 11), w1b = __shfl(w1, gbase + 11);
                    float w0c = __shfl(w0, gbase + 12), w1c = __shfl(w1, gbase + 12);
                    float w0d = __shfl(w0, gbase + 13), w1d = __shfl(w1, gbase + 13);
                    float w0e = __shfl(w0, gbase + 14), w1e = __shfl(w1, gbase + 14);
                    float w0f = __shfl(w0, gbase + 15), w1f = __shfl(w1, gbase + 15);
                    EDGE_FMA(v8,  w08, w18) EDGE_FMA(v9,  w09, w19)
                    EDGE_FMA(v10, w0a, w1a) EDGE_FMA(v11, w0b, w1b)
                    EDGE_FMA(v12, w0c, w1c) EDGE_FMA(v13, w0d, w1d)
                    EDGE_FMA(v14, w0e, w1e) EDGE_FMA(v15, w0f, w1f)
                }
            }
        }
        // normalize (x0.5 head mean), pack fp16, stage to LDS
        float r0s = 0.5f / (d0 + 1e-16f);
        float r1s = 0.5f / (d1 + 1e-16f);
        Ash[r * 66 + h2i]          = f16pack2(A0[0] * r0s, A0[1] * r0s);
        Ash[r * 66 + h2i + 1]      = f16pack2(A0[2] * r0s, A0[3] * r0s);
        Ash[r * 66 + 32 + h2i]     = f16pack2(A1[0] * r1s, A1[1] * r1s);
        Ash[r * 66 + 32 + h2i + 1] = f16pack2(A1[2] * r1s, A1[3] * r1s);
    }
    #undef EDGE_FMA
    __syncthreads();

    // GEMM: out[base+row][c] = A0@Wg0 + A1@Wg1 + bg ; 4 rows x 4 cols/thread
    const int r0 = (t >> 4) * 4, c0 = (t & 15) * 4;
    const float4 bg = *(const float4*)&bgat[c0];
    float4 acc0 = bg, acc1 = bg, acc2 = bg, acc3 = bg;
    #pragma unroll 4
    for (int kk = 0; kk < 32; kk++) {
        // W rows 2kk, 2kk+1 for both heads (L1-broadcast)
        float4 w0e = f16unpack4(*(const uint2*)&Wgh[(2 * kk)     * 64 + (c0 >> 1)]);
        float4 w0o = f16unpack4(*(const uint2*)&Wgh[(2 * kk + 1) * 64 + (c0 >> 1)]);
        float4 w1e = f16unpack4(*(const uint2*)&Wgh[(2 * kk)     * 64 + 32 + (c0 >> 1)]);
        float4 w1o = f16unpack4(*(const uint2*)&Wgh[(2 * kk + 1) * 64 + 32 + (c0 >> 1)]);
        #define GA_ROW(j, accj)                                                     \
            { float2 a0 = f16unpack2(Ash[(r0 + j) * 66 + kk]);                      \
              float2 a1 = f16unpack2(Ash[(r0 + j) * 66 + 32 + kk]);                 \
              accj.x = fmaf(a0.x, w0e.x, accj.x); accj.y = fmaf(a0.x, w0e.y, accj.y); \
              accj.z = fmaf(a0.x, w0e.z, accj.z); accj.w = fmaf(a0.x, w0e.w, accj.w); \
              accj.x = fmaf(a0.y, w0o.x, accj.x); accj.y = fmaf(a0.y, w0o.y, accj.y); \
              accj.z = fmaf(a0.y, w0o.z, accj.z); accj.w = fmaf(a0.y, w0o.w, accj.w); \
              accj.x = fmaf(a1.x, w1e.x, accj.x); accj.y = fmaf(a1.x, w1e.y, accj.y); \
              accj.z = fmaf(a1.x, w1e.z, accj.z); accj.w = fmaf(a1.x, w1e.w, accj.w); \
              accj.x = fmaf(a1.y, w1o.x, accj.x); accj.y = fmaf(a1.y, w1o.y, accj.y); \
              accj.z = fmaf(a1.y, w1o.z, accj.z); accj.w = fmaf(a1.y, w1o.w, accj.w); }
        GA_ROW(0, acc0) GA_ROW(1, acc1) GA_ROW(2, acc2) GA_ROW(3, acc3)
        #undef GA_ROW
    }
    #define GA_STORE(j, accj)                                                   \
        { int row = base + r0 + j;                                              \
          if (row < n) *(float4*)&OUT[(size_t)row * 64 + c0] = accj; }
    GA_STORE(0, acc0) GA_STORE(1, acc1) GA_STORE(2, acc2) GA_STORE(3, acc3)
    #undef GA_STORE
}

extern "C" void kernel_launch(void* const* d_in, const int* in_sizes, int n_in,
                              void* d_out, int out_size, void* d_ws, size_t ws_size,
                              hipStream_t stream) {
    const float* x   = (const float*)d_in[0];
    const int*   ei  = (const int*)d_in[1];
    const float* ea  = (const float*)d_in[2];
    const int N = in_sizes[0] / 64;
    const int E = in_sizes[1] / 2;
    const int* src = ei;
    const int* dst = ei + E;

    const float* wn[3] = {(const float*)d_in[3],  (const float*)d_in[9],  (const float*)d_in[15]};
    const float* bn[3] = {(const float*)d_in[4],  (const float*)d_in[10], (const float*)d_in[16]};
    const float* we[3] = {(const float*)d_in[5],  (const float*)d_in[11], (const float*)d_in[17]};
    const float* be[3] = {(const float*)d_in[6],  (const float*)d_in[12], (const float*)d_in[18]};
    const float* wc[3] = {(const float*)d_in[7],  (const float*)d_in[13], (const float*)d_in[19]};
    const float* bc[3] = {(const float*)d_in[8],  (const float*)d_in[14], (const float*)d_in[20]};
    const float* wgat    = (const float*)d_in[21];
    const float* att_src = (const float*)d_in[22];
    const float* att_dst = (const float*)d_in[23];
    const float* bgat    = (const float*)d_in[24];

    // workspace carve-up (256B aligned)
    char* ws = (char*)d_ws;
    size_t off = 0;
    auto alloc = [&](size_t bytes) -> void* {
        void* p = ws + off;
        off = (off + bytes + 255) & ~(size_t)255;
        return p;
    };
    int*   row_start = (int*)alloc((size_t)(N + 1) * 4);
    int*   partials  = (int*)alloc(1024 * 4);
    int*   rank      = (int*)alloc((size_t)E * 4);
    int2*  csr_se    = (int2*)alloc((size_t)E * 8);
    float* Wc        = (float*)alloc((size_t)3 * 4480 * 4);   // per layer: W1|W2|cv
    u32*   Wgh       = (u32*)alloc((size_t)4096 * 4);         // Wg fp16 [64][64] u32
    float* vsd       = (float*)alloc((size_t)256 * 4);        // folded score vecs [4][64]
    float* B5        = (float*)alloc((size_t)N * 5 * 4);
    u32*   xh        = (u32*)alloc((size_t)N * 64 * 2);       // x fp16 [N][64]
    u32*   bufH0     = (u32*)alloc((size_t)N * 64 * 2);       // h ping (fp16 [N][64])
    u32*   bufH1     = (u32*)alloc((size_t)N * 64 * 2);       // h pong (fp16 [N][64])
    float* asrc      = (float*)alloc((size_t)N * 2 * 4);
    float* adst      = (float*)alloc((size_t)N * 2 * 4);
    float* out = (float*)d_out;

    const int nbN = (N + TPB - 1) / TPB;
    const int nbE = (E + TPB - 1) / TPB;
    const int tiles = (N + 63) / 64;
    const int n8 = N * 8;
    const int nbC = (n8 + TPB - 1) / TPB;
    const int nbZ = (N + 1 + TPB - 1) / TPB;

    // ---- mega-prep: folds + Wg pack + vsd + x cvt + row_start zero ----
    CombPtrs p0 = {wn[0], bn[0], we[0], be[0], wc[0], bc[0], Wc};
    CombPtrs p1 = {wn[1], bn[1], we[1], be[1], wc[1], bc[1], Wc + 4480};
    CombPtrs p2 = {wn[2], bn[2], we[2], be[2], wc[2], bc[2], Wc + 2 * 4480};
    k_prep<<<4 + nbC + nbZ, TPB, 0, stream>>>(p0, p1, p2, wgat, Wgh,
                                              att_src, att_dst, vsd,
                                              (const float4*)x, (uint4*)xh, n8, nbC,
                                              row_start, N + 1);

    // ---- CSR build: hist(+rank), scan1, scan3(self-prefix), scatter ----
    k_hist<<<nbE, TPB, 0, stream>>>(dst, row_start, rank, E);
    k_scan1<<<nbN, TPB, 0, stream>>>(row_start, partials, N);
    k_scan3<<<nbN, TPB, 0, stream>>>(row_start, partials, N, E);
    k_scatter<<<nbE, TPB, 0, stream>>>(src, dst, rank, row_start, csr_se, E);

    // ---- 3 fused edge-conv layers (EC1 computes B5; EC3 computes scores) ---
    k_ec_fused<true, true, false, true><<<tiles, TPB, 0, stream>>>(
        xh,    row_start, csr_se, Wc,            B5, ea, bufH0, N,
        nullptr, nullptr, nullptr);
    k_ec_fused<true, true, false, false><<<tiles, TPB, 0, stream>>>(
        bufH0, row_start, csr_se, Wc + 4480,     B5, nullptr, bufH1, N,
        nullptr, nullptr, nullptr);
    k_ec_fused<true, true, true, false><<<tiles, TPB, 0, stream>>>(
        bufH1, row_start, csr_se, Wc + 2 * 4480, B5, nullptr, bufH0, N,
        vsd, asrc, adst);

    // ---- GAT aggregation (h3-space, pipelined ladder) + micro-tiled GEMM ---
    k_gat_agg<<<tiles, TPB, 0, stream>>>(bufH0, row_start, csr_se, asrc, adst,
                                         Wgh, bgat, out, N);
}

// Round 11
// 408.380 us; speedup vs baseline: 1.1880x; 1.1880x over previous
//
#include <hip/hip_runtime.h>
#include <hip/hip_fp16.h>
#include <math.h>

// ---------------------------------------------------------------------------
// GraphNet: 3x EdgeConv (fully linearized) + GAT(2 heads, concat=False)
//
// out[d] = relu( (Σ_{e→d} h[src_e]) @ W1 + B5[d] @ W2 + deg[d]·c )
//
// R18 = CLEAN REVERT to R14 (best verified: 409.1us, absmax 0.25).
// R15-R17 h3-space excursion ledger: 458, 421, 485 — all lost to R14.
//   R17 lesson (stone): conditionally-defined prefetch registers consumed
//   after an intervening region SPILL TO SCRATCH (WRITE 36->126MB) — a
//   prefetch that spills is worse than no prefetch.
//   R15 lesson (stone): gather time ∝ in-flight lines (>=8/lane), not bytes.
// R14 (stone): launch gaps ~0; dispatch count irrelevant.
// R12 (stone): two weight streams from global thrash L1 (32KB) — stage one
//   in LDS. R11 (stone): per-edge LDS atomics poison; src-sort no help.
// Precision: x,h fp16 storage / fp32 accum; G fp16; Wg fp16 (absmax G-dom).
// ---------------------------------------------------------------------------

#define TPB 256

typedef unsigned int u32;

__device__ inline float2 f16unpack2(u32 u) {
    __half2 h = *reinterpret_cast<__half2*>(&u);
    return __half22float2(h);
}
__device__ inline float4 f16unpack4(uint2 q) {
    float2 a = f16unpack2(q.x), b = f16unpack2(q.y);
    return make_float4(a.x, a.y, b.x, b.y);
}
__device__ inline u32 f16pack2(float lo, float hi) {
    __half2 h = __floats2half2_rn(lo, hi);
    return *reinterpret_cast<u32*>(&h);
}
__device__ inline void fma_f16x8(float* acc, uint4 v, float w) {
    float2 t;
    t = f16unpack2(v.x); acc[0] = fmaf(w, t.x, acc[0]); acc[1] = fmaf(w, t.y, acc[1]);
    t = f16unpack2(v.y); acc[2] = fmaf(w, t.x, acc[2]); acc[3] = fmaf(w, t.y, acc[3]);
    t = f16unpack2(v.z); acc[4] = fmaf(w, t.x, acc[4]); acc[5] = fmaf(w, t.y, acc[5]);
    t = f16unpack2(v.w); acc[6] = fmaf(w, t.x, acc[6]); acc[7] = fmaf(w, t.y, acc[7]);
}
__device__ inline void acc_h16(float4& acc, uint2 v) {
    float2 a = f16unpack2(v.x);
    float2 b = f16unpack2(v.y);
    acc.x += a.x; acc.y += a.y; acc.z += b.x; acc.w += b.y;
}

#define MAC4(acc, a, w0, w1, w2, w3)                                           \
    acc.x = fmaf(a.x, w0.x, acc.x); acc.y = fmaf(a.x, w0.y, acc.y);            \
    acc.z = fmaf(a.x, w0.z, acc.z); acc.w = fmaf(a.x, w0.w, acc.w);            \
    acc.x = fmaf(a.y, w1.x, acc.x); acc.y = fmaf(a.y, w1.y, acc.y);            \
    acc.z = fmaf(a.y, w1.z, acc.z); acc.w = fmaf(a.y, w1.w, acc.w);            \
    acc.x = fmaf(a.z, w2.x, acc.x); acc.y = fmaf(a.z, w2.y, acc.y);            \
    acc.z = fmaf(a.z, w2.z, acc.z); acc.w = fmaf(a.z, w2.w, acc.w);            \
    acc.x = fmaf(a.w, w3.x, acc.x); acc.y = fmaf(a.w, w3.y, acc.y);            \
    acc.z = fmaf(a.w, w3.z, acc.z); acc.w = fmaf(a.w, w3.w, acc.w);

// ------- mega-prep: weight folds + Wg fp16 pack + x cvt + row_start zero ----
struct CombPtrs {
    const float* wn; const float* bn;
    const float* we; const float* be;
    const float* wc; const float* bc;
    float* W1;   // W1(4096) | W2(320) | cv(64)
};

__global__ __launch_bounds__(TPB) void k_prep(CombPtrs p0, CombPtrs p1, CombPtrs p2,
                                              const float* __restrict__ wg, u32* __restrict__ wgh,
                                              const float4* __restrict__ X, uint4* __restrict__ XH,
                                              int n8, int nbC,
                                              int* __restrict__ rs, int nz) {
    const int b = blockIdx.x;
    if (b >= 4 + nbC) {
        // zero row_start
        int i = (b - 4 - nbC) * TPB + threadIdx.x;
        if (i < nz) rs[i] = 0;
        return;
    }
    if (b >= 4) {
        // x fp32 -> fp16
        int i = (b - 4) * TPB + threadIdx.x;
        if (i < n8) {
            float4 a = X[i * 2], c = X[i * 2 + 1];
            uint4 o;
            o.x = f16pack2(a.x, a.y); o.y = f16pack2(a.z, a.w);
            o.z = f16pack2(c.x, c.y); o.w = f16pack2(c.z, c.w);
            XH[i] = o;
        }
        return;
    }
    if (b == 3) {
        // pack Wg [64][128] fp32 -> [64][64] u32 (half2 pairs)
        for (int i = threadIdx.x; i < 4096; i += TPB) {
            float2 v = *(const float2*)&wg[i * 2];
            wgh[i] = f16pack2(v.x, v.y);
        }
        return;
    }
    CombPtrs P = (b == 0) ? p0 : ((b == 1) ? p1 : p2);
    const float* wn = P.wn; const float* bn = P.bn;
    const float* we = P.we; const float* be = P.be;
    const float* wc = P.wc; const float* bc = P.bc;
    float* W1 = P.W1;
    float* W2 = P.W1 + 4096;
    float* cv = P.W1 + 4416;
    int tid = threadIdx.x;
    for (int idx = tid; idx < 64 * 64; idx += TPB) {
        int i = idx >> 6, j = idx & 63;
        float acc = 0.f;
        #pragma unroll 8
        for (int k = 0; k < 64; k++) acc = fmaf(wn[i * 64 + k], wc[k * 64 + j], acc);
        W1[idx] = acc;
    }
    for (int idx = tid; idx < 5 * 64; idx += TPB) {
        int i = idx >> 6, j = idx & 63;
        float acc = 0.f;
        #pragma unroll 8
        for (int k = 0; k < 64; k++) acc = fmaf(we[i * 64 + k], wc[(64 + k) * 64 + j], acc);
        W2[idx] = acc;
    }
    for (int j = tid; j < 64; j += TPB) {
        float acc = bc[j];
        for (int k = 0; k < 64; k++) {
            acc = fmaf(bn[k], wc[k * 64 + j], acc);
            acc = fmaf(be[k], wc[(64 + k) * 64 + j], acc);
        }
        cv[j] = acc;
    }
}

// ---- k_hist: degree histogram + edge rank (atomicAdd return) ---------------
__global__ __launch_bounds__(TPB) void k_hist(const int* __restrict__ dst, int* __restrict__ cnt,
                                              int* __restrict__ rank, int E) {
    int e = blockIdx.x * TPB + threadIdx.x;
    if (e < E) rank[e] = atomicAdd(&cnt[dst[e]], 1);
}

// ---------------- scan (exclusive; scan1 + self-service scan3) --------------
__global__ __launch_bounds__(TPB) void k_scan1(int* __restrict__ data, int* __restrict__ partials, int n) {
    __shared__ int s[TPB];
    int i = blockIdx.x * TPB + threadIdx.x;
    int v = (i < n) ? data[i] : 0;
    s[threadIdx.x] = v;
    __syncthreads();
    for (int off = 1; off < TPB; off <<= 1) {
        int t = (threadIdx.x >= off) ? s[threadIdx.x - off] : 0;
        __syncthreads();
        s[threadIdx.x] += t;
        __syncthreads();
    }
    if (i < n) data[i] = s[threadIdx.x] - v;  // exclusive
    if (threadIdx.x == TPB - 1) partials[blockIdx.x] = s[TPB - 1];
}

// each block sums partials[0..bid) itself (<=400 ints, L2-hit) — no scan2
__global__ __launch_bounds__(TPB) void k_scan3(int* __restrict__ data, const int* __restrict__ partials,
                                               int n, int total) {
    const int bid = blockIdx.x;
    int s = 0;
    for (int j = threadIdx.x; j < bid; j += TPB) s += partials[j];
    #pragma unroll
    for (int off = 32; off > 0; off >>= 1) s += __shfl_down(s, off);
    __shared__ int ws[4];
    if ((threadIdx.x & 63) == 0) ws[threadIdx.x >> 6] = s;
    __syncthreads();
    int pre = ws[0] + ws[1] + ws[2] + ws[3];
    int i = bid * TPB + threadIdx.x;
    if (i < n) data[i] += pre;
    if (i == 0) data[n] = total;
}

// ---- atomic-free scatter: one combined int2{src,e} random 8B stream --------
__global__ __launch_bounds__(TPB) void k_scatter(const int* __restrict__ src, const int* __restrict__ dst,
                                                 const int* __restrict__ rank, const int* __restrict__ row_start,
                                                 int2* __restrict__ csr_se, int E) {
    int e = blockIdx.x * TPB + threadIdx.x;
    if (e < E) {
        int idx = row_start[dst[e]] + rank[e];
        csr_se[idx] = make_int2(src[e], e);
    }
}

// ---- fused EC layer: group-gather into LDS A-tile, then tiled GEMM ---------
// IN16: H rows are 64 halves (128 B); else 64 floats (256 B).
// OUT16: result stored fp16 (one rounding; accumulation fp32).
// GAT: keep relu(h3) tile in LDS, run GAT GEMM + att scores here (Wg fp16
//   staged in LDS — R12/R13 L1-thrash lesson).
// B5C: compute B5 = Σ ea during the gather (lane-own-edge accumulate +
//   16-lane shfl reduce; identical partition to old k_aggB5), write global
//   B5 for later layers, use local LDS copy in this layer's epilogue.
template <bool IN16, bool OUT16, bool GAT, bool B5C>
__global__ __launch_bounds__(TPB, 6) void k_ec_fused(const void* __restrict__ Hv,
                                                     const int* __restrict__ row_start,
                                                     const int2* __restrict__ csr_se,
                                                     const float* __restrict__ Wfold,  // W1(4096)|W2(320)|cv(64)
                                                     float* __restrict__ B5,
                                                     const float* __restrict__ EA,
                                                     void* __restrict__ OUTv, int n,
                                                     const u32* __restrict__ Wgh,      // [64][64] u32 fp16 (GAT)
                                                     const float* __restrict__ att_src,
                                                     const float* __restrict__ att_dst,
                                                     u32* __restrict__ Gh,
                                                     float* __restrict__ asrc,
                                                     float* __restrict__ adst) {
    __shared__ float Alds[64 * 68];
    __shared__ u32 Wglds[GAT ? 4096 : 4];
    __shared__ float Blds[B5C ? 320 : 4];
    const float* Hf = (const float*)Hv;
    const u32*   Hh = (const u32*)Hv;     // [N][32] u32 = [N][64] half
    const int t = threadIdx.x;
    const int base = blockIdx.x * 64;

    if (GAT) {
        // stage Wg fp16 (16KB) — first use is several barriers later
        #pragma unroll
        for (int rep = 0; rep < 4; rep++) {
            int i = rep * 256 + t;
            *(uint4*)&Wglds[i * 4] = ((const uint4*)Wgh)[i];
        }
    }

    // gather phase: 16 lane-groups, 4 rows each, 8-deep load ladder
    const int lane = t & 63;
    const int lid = lane & 15;
    const int gbase = lane & 48;
    const int gid = t >> 4;
    const int c4 = lid * 4;          // float col for this lane
    const int h2i = lid * 2;         // u32 index into fp16 row
    for (int i = 0; i < 4; i++) {
        int r = gid * 4 + i;
        int node = base + r;
        float4 acc = make_float4(0.f, 0.f, 0.f, 0.f);
        float b0 = 0.f, b1 = 0.f, b2 = 0.f, b3 = 0.f, b4 = 0.f;
        if (node < n) {
            int beg = row_start[node], end = row_start[node + 1];
            for (int chunk = beg; chunk < end; chunk += 16) {
                int cdeg = min(end - chunk, 16);
                bool ev = (chunk + lid < end);
                int2 se = ev ? csr_se[chunk + lid] : make_int2(0, 0);
                int s_l = se.x;
                if (B5C && ev) {
                    const float* p = EA + (size_t)se.y * 5;
                    b0 += p[0]; b1 += p[1]; b2 += p[2]; b3 += p[3]; b4 += p[4];
                }
                int it = 0;
                for (; it + 7 < cdeg; it += 8) {
                    int se0 = __shfl(s_l, gbase + it);
                    int se1 = __shfl(s_l, gbase + it + 1);
                    int se2 = __shfl(s_l, gbase + it + 2);
                    int se3 = __shfl(s_l, gbase + it + 3);
                    int se4 = __shfl(s_l, gbase + it + 4);
                    int se5 = __shfl(s_l, gbase + it + 5);
                    int se6 = __shfl(s_l, gbase + it + 6);
                    int se7 = __shfl(s_l, gbase + it + 7);
                    if (IN16) {
                        uint2 v0 = *(const uint2*)&Hh[(size_t)se0 * 32 + h2i];
                        uint2 v1 = *(const uint2*)&Hh[(size_t)se1 * 32 + h2i];
                        uint2 v2 = *(const uint2*)&Hh[(size_t)se2 * 32 + h2i];
                        uint2 v3 = *(const uint2*)&Hh[(size_t)se3 * 32 + h2i];
                        uint2 v4 = *(const uint2*)&Hh[(size_t)se4 * 32 + h2i];
                        uint2 v5 = *(const uint2*)&Hh[(size_t)se5 * 32 + h2i];
                        uint2 v6 = *(const uint2*)&Hh[(size_t)se6 * 32 + h2i];
                        uint2 v7 = *(const uint2*)&Hh[(size_t)se7 * 32 + h2i];
                        acc_h16(acc, v0); acc_h16(acc, v1); acc_h16(acc, v2); acc_h16(acc, v3);
                        acc_h16(acc, v4); acc_h16(acc, v5); acc_h16(acc, v6); acc_h16(acc, v7);
                    } else {
                        float4 v0 = *(const float4*)&Hf[(size_t)se0 * 64 + c4];
                        float4 v1 = *(const float4*)&Hf[(size_t)se1 * 64 + c4];
                        float4 v2 = *(const float4*)&Hf[(size_t)se2 * 64 + c4];
                        float4 v3 = *(const float4*)&Hf[(size_t)se3 * 64 + c4];
                        float4 v4 = *(const float4*)&Hf[(size_t)se4 * 64 + c4];
                        float4 v5 = *(const float4*)&Hf[(size_t)se5 * 64 + c4];
                        float4 v6 = *(const float4*)&Hf[(size_t)se6 * 64 + c4];
                        float4 v7 = *(const float4*)&Hf[(size_t)se7 * 64 + c4];
                        acc.x += ((v0.x + v1.x) + (v2.x + v3.x)) + ((v4.x + v5.x) + (v6.x + v7.x));
                        acc.y += ((v0.y + v1.y) + (v2.y + v3.y)) + ((v4.y + v5.y) + (v6.y + v7.y));
                        acc.z += ((v0.z + v1.z) + (v2.z + v3.z)) + ((v4.z + v5.z) + (v6.z + v7.z));
                        acc.w += ((v0.w + v1.w) + (v2.w + v3.w)) + ((v4.w + v5.w) + (v6.w + v7.w));
                    }
                }
                for (; it + 3 < cdeg; it += 4) {
                    int se0 = __shfl(s_l, gbase + it);
                    int se1 = __shfl(s_l, gbase + it + 1);
                    int se2 = __shfl(s_l, gbase + it + 2);
                    int se3 = __shfl(s_l, gbase + it + 3);
                    if (IN16) {
                        uint2 v0 = *(const uint2*)&Hh[(size_t)se0 * 32 + h2i];
                        uint2 v1 = *(const uint2*)&Hh[(size_t)se1 * 32 + h2i];
                        uint2 v2 = *(const uint2*)&Hh[(size_t)se2 * 32 + h2i];
                        uint2 v3 = *(const uint2*)&Hh[(size_t)se3 * 32 + h2i];
                        acc_h16(acc, v0); acc_h16(acc, v1); acc_h16(acc, v2); acc_h16(acc, v3);
                    } else {
                        float4 v0 = *(const float4*)&Hf[(size_t)se0 * 64 + c4];
                        float4 v1 = *(const float4*)&Hf[(size_t)se1 * 64 + c4];
                        float4 v2 = *(const float4*)&Hf[(size_t)se2 * 64 + c4];
                        float4 v3 = *(const float4*)&Hf[(size_t)se3 * 64 + c4];
                        acc.x += (v0.x + v1.x) + (v2.x + v3.x);
                        acc.y += (v0.y + v1.y) + (v2.y + v3.y);
                        acc.z += (v0.z + v1.z) + (v2.z + v3.z);
                        acc.w += (v0.w + v1.w) + (v2.w + v3.w);
                    }
                }
                for (; it < cdeg; it++) {
                    int se_ = __shfl(s_l, gbase + it);
                    if (IN16) {
                        uint2 v = *(const uint2*)&Hh[(size_t)se_ * 32 + h2i];
                        acc_h16(acc, v);
                    } else {
                        float4 v = *(const float4*)&Hf[(size_t)se_ * 64 + c4];
                        acc.x += v.x; acc.y += v.y; acc.z += v.z; acc.w += v.w;
                    }
                }
            }
        }
        *(float4*)&Alds[r * 68 + c4] = acc;
        if (B5C) {
            #pragma unroll
            for (int off = 1; off < 16; off <<= 1) {
                b0 += __shfl_xor(b0, off); b1 += __shfl_xor(b1, off);
                b2 += __shfl_xor(b2, off); b3 += __shfl_xor(b3, off);
                b4 += __shfl_xor(b4, off);
            }
            if (lid == 0 && node < n) {
                Blds[r * 5 + 0] = b0; Blds[r * 5 + 1] = b1; Blds[r * 5 + 2] = b2;
                Blds[r * 5 + 3] = b3; Blds[r * 5 + 4] = b4;
                float* bp = B5 + (size_t)node * 5;
                bp[0] = b0; bp[1] = b1; bp[2] = b2; bp[3] = b3; bp[4] = b4;
            }
        }
    }
    __syncthreads();

    // GEMM phase — A from LDS, Wfold straight from global (L1 broadcast)
    const int r0 = (t >> 4) * 4, c0 = (t & 15) * 4;
    float4 acc0 = make_float4(0.f, 0.f, 0.f, 0.f), acc1 = acc0, acc2 = acc0, acc3 = acc0;
    #pragma unroll 2
    for (int k = 0; k < 64; k += 4) {
        float4 a0 = *(float4*)&Alds[(r0 + 0) * 68 + k];
        float4 a1 = *(float4*)&Alds[(r0 + 1) * 68 + k];
        float4 a2 = *(float4*)&Alds[(r0 + 2) * 68 + k];
        float4 a3 = *(float4*)&Alds[(r0 + 3) * 68 + k];
        float4 w0 = *(const float4*)&Wfold[(k + 0) * 64 + c0];
        float4 w1 = *(const float4*)&Wfold[(k + 1) * 64 + c0];
        float4 w2 = *(const float4*)&Wfold[(k + 2) * 64 + c0];
        float4 w3 = *(const float4*)&Wfold[(k + 3) * 64 + c0];
        MAC4(acc0, a0, w0, w1, w2, w3);
        MAC4(acc1, a1, w0, w1, w2, w3);
        MAC4(acc2, a2, w0, w1, w2, w3);
        MAC4(acc3, a3, w0, w1, w2, w3);
    }
    float4 w2c[5];
    #pragma unroll
    for (int j = 0; j < 5; j++) w2c[j] = *(const float4*)&Wfold[4096 + j * 64 + c0];
    const float4 cv4 = *(const float4*)&Wfold[4416 + c0];

    if (GAT) __syncthreads();   // all GEMM reads of Alds done before overwrite

    #define EC_STORE(i, acc)                                                        \
        { int row = base + r0 + i;                                                  \
          if (row < n) {                                                            \
              float deg = (float)(row_start[row + 1] - row_start[row]);             \
              float4 q;                                                             \
              q.x = deg * cv4.x; q.y = deg * cv4.y;                                 \
              q.z = deg * cv4.z; q.w = deg * cv4.w;                                 \
              for (int j = 0; j < 5; j++) {                                         \
                  float b = B5C ? Blds[(r0 + i) * 5 + j] : B5[(size_t)row * 5 + j]; \
                  q.x = fmaf(b, w2c[j].x, q.x); q.y = fmaf(b, w2c[j].y, q.y);       \
                  q.z = fmaf(b, w2c[j].z, q.z); q.w = fmaf(b, w2c[j].w, q.w);       \
              }                                                                     \
              float4 r4;                                                            \
              r4.x = fmaxf(acc.x + q.x, 0.f); r4.y = fmaxf(acc.y + q.y, 0.f);       \
              r4.z = fmaxf(acc.z + q.z, 0.f); r4.w = fmaxf(acc.w + q.w, 0.f);       \
              if (GAT) {                                                            \
                  *(float4*)&Alds[(r0 + i) * 68 + c0] = r4;                         \
              } else if (OUT16) {                                                   \
                  u32* O = (u32*)OUTv;                                              \
                  uint2 gg;                                                         \
                  gg.x = f16pack2(r4.x, r4.y); gg.y = f16pack2(r4.z, r4.w);         \
                  *(uint2*)&O[(size_t)row * 32 + (c0 >> 1)] = gg;                   \
              } else {                                                              \
                  float* O = (float*)OUTv;                                          \
                  *(float4*)&O[(size_t)row * 64 + c0] = r4;                         \
              } } }
    EC_STORE(0, acc0) EC_STORE(1, acc1) EC_STORE(2, acc2) EC_STORE(3, acc3)
    #undef EC_STORE

    if (GAT) {
        __syncthreads();   // Alds now holds relu(h3) tile
        float4 p00 = make_float4(0.f, 0.f, 0.f, 0.f), p01 = p00, p02 = p00, p03 = p00;
        float4 p10 = p00, p11 = p00, p12 = p00, p13 = p00;
        #pragma unroll 2
        for (int k = 0; k < 64; k += 4) {
            float4 a0 = *(float4*)&Alds[(r0 + 0) * 68 + k];
            float4 a1 = *(float4*)&Alds[(r0 + 1) * 68 + k];
            float4 a2 = *(float4*)&Alds[(r0 + 2) * 68 + k];
            float4 a3 = *(float4*)&Alds[(r0 + 3) * 68 + k];
            // head0 cols c0..c0+3 = u32 (c0>>1); head1 = +32
            float4 u0 = f16unpack4(*(uint2*)&Wglds[(k + 0) * 64 + (c0 >> 1)]);
            float4 u1 = f16unpack4(*(uint2*)&Wglds[(k + 1) * 64 + (c0 >> 1)]);
            float4 u2 = f16unpack4(*(uint2*)&Wglds[(k + 2) * 64 + (c0 >> 1)]);
            float4 u3 = f16unpack4(*(uint2*)&Wglds[(k + 3) * 64 + (c0 >> 1)]);
            MAC4(p00, a0, u0, u1, u2, u3);
            MAC4(p01, a1, u0, u1, u2, u3);
            MAC4(p02, a2, u0, u1, u2, u3);
            MAC4(p03, a3, u0, u1, u2, u3);
            float4 v0 = f16unpack4(*(uint2*)&Wglds[(k + 0) * 64 + 32 + (c0 >> 1)]);
            float4 v1 = f16unpack4(*(uint2*)&Wglds[(k + 1) * 64 + 32 + (c0 >> 1)]);
            float4 v2 = f16unpack4(*(uint2*)&Wglds[(k + 2) * 64 + 32 + (c0 >> 1)]);
            float4 v3 = f16unpack4(*(uint2*)&Wglds[(k + 3) * 64 + 32 + (c0 >> 1)]);
            MAC4(p10, a0, v0, v1, v2, v3);
            MAC4(p11, a1, v0, v1, v2, v3);
            MAC4(p12, a2, v0, v1, v2, v3);
            MAC4(p13, a3, v0, v1, v2, v3);
        }
        const float4 as0 = *(const float4*)&att_src[c0];
        const float4 as1 = *(const float4*)&att_src[64 + c0];
        const float4 ad0 = *(const float4*)&att_dst[c0];
        const float4 ad1 = *(const float4*)&att_dst[64 + c0];
        #define DOT4(a, b) (a.x * b.x + a.y * b.y + a.z * b.z + a.w * b.w)
        #define GAT_ROW(i, h0, h1)                                                      \
            { int row = base + r0 + i;                                                  \
              float s0 = DOT4(h0, as0), s1 = DOT4(h1, as1);                             \
              float d0 = DOT4(h0, ad0), d1 = DOT4(h1, ad1);                             \
              s0 += __shfl_xor(s0, 1); s1 += __shfl_xor(s1, 1);                         \
              d0 += __shfl_xor(d0, 1); d1 += __shfl_xor(d1, 1);                         \
              s0 += __shfl_xor(s0, 2); s1 += __shfl_xor(s1, 2);                         \
              d0 += __shfl_xor(d0, 2); d1 += __shfl_xor(d1, 2);                         \
              s0 += __shfl_xor(s0, 4); s1 += __shfl_xor(s1, 4);                         \
              d0 += __shfl_xor(d0, 4); d1 += __shfl_xor(d1, 4);                         \
              s0 += __shfl_xor(s0, 8); s1 += __shfl_xor(s1, 8);                         \
              d0 += __shfl_xor(d0, 8); d1 += __shfl_xor(d1, 8);                         \
              if (row < n) {                                                            \
                  uint2 g0; g0.x = f16pack2(h0.x, h0.y); g0.y = f16pack2(h0.z, h0.w);   \
                  uint2 g1; g1.x = f16pack2(h1.x, h1.y); g1.y = f16pack2(h1.z, h1.w);   \
                  *(uint2*)&Gh[(size_t)row * 64 + (c0 >> 1)] = g0;                      \
                  *(uint2*)&Gh[(size_t)row * 64 + 32 + (c0 >> 1)] = g1;                 \
                  if ((t & 15) == 0) {                                                  \
                      float2 sv; sv.x = s0; sv.y = s1;                                  \
                      float2 dv; dv.x = d0; dv.y = d1;                                  \
                      *(float2*)&asrc[(size_t)row * 2] = sv;                            \
                      *(float2*)&adst[(size_t)row * 2] = dv; } } }
        GAT_ROW(0, p00, p10) GAT_ROW(1, p01, p11) GAT_ROW(2, p02, p12) GAT_ROW(3, p03, p13)
        #undef GAT_ROW
        #undef DOT4
    }
}

// ----- GAT aggregation: fp16 G; one node per 16-lane group; head=lid>>3 -----
__global__ __launch_bounds__(TPB) void k_gat_agg(const u32* __restrict__ Gh, const int* __restrict__ row_start,
                                                 const int2* __restrict__ csr_se, const float* __restrict__ asrc,
                                                 const float* __restrict__ adst, const float* __restrict__ bgat,
                                                 float* __restrict__ OUT, int n) {
    const int node = blockIdx.x * 16 + (threadIdx.x >> 4);
    if (node >= n) return;
    const int lane = threadIdx.x & 63;
    const int lid = lane & 15;
    const int gbase = lane & 48;
    const int head = lid >> 3;
    const int u4 = lid * 4;
    const int beg = row_start[node], end = row_start[node + 1];
    const float2 adv = *(const float2*)&adst[(size_t)node * 2];
    float m0 = -INFINITY, m1 = -INFINITY, d0 = 0.f, d1 = 0.f;
    float A[8] = {0.f, 0.f, 0.f, 0.f, 0.f, 0.f, 0.f, 0.f};
    for (int chunk = beg; chunk < end; chunk += 16) {
        int cdeg = min(end - chunk, 16);
        bool valid = (lid < cdeg);
        int s_l = valid ? csr_se[chunk + lid].x : 0;
        float al0 = -INFINITY, al1 = -INFINITY;
        if (valid) {
            float2 av = *(const float2*)&asrc[(size_t)s_l * 2];
            float t0 = av.x + adv.x, t1 = av.y + adv.y;
            al0 = (t0 > 0.f) ? t0 : 0.2f * t0;
            al1 = (t1 > 0.f) ? t1 : 0.2f * t1;
        }
        float cm0 = al0, cm1 = al1;
        #pragma unroll
        for (int off = 1; off < 16; off <<= 1) {
            cm0 = fmaxf(cm0, __shfl_xor(cm0, off));
            cm1 = fmaxf(cm1, __shfl_xor(cm1, off));
        }
        float nm0 = fmaxf(m0, cm0), nm1 = fmaxf(m1, cm1);
        float sc0 = __expf(m0 - nm0), sc1 = __expf(m1 - nm1);  // 0 on first chunk
        float w0 = valid ? __expf(al0 - nm0) : 0.f;
        float w1 = valid ? __expf(al1 - nm1) : 0.f;
        float cd0 = w0, cd1 = w1;
        #pragma unroll
        for (int off = 1; off < 16; off <<= 1) {
            cd0 += __shfl_xor(cd0, off);
            cd1 += __shfl_xor(cd1, off);
        }
        d0 = d0 * sc0 + cd0;
        d1 = d1 * sc1 + cd1;
        float scsel = head ? sc1 : sc0;
        #pragma unroll
        for (int j = 0; j < 8; j++) A[j] *= scsel;
        m0 = nm0; m1 = nm1;
        int it = 0;
        for (; it + 3 < cdeg; it += 4) {
            int sa = __shfl(s_l, gbase + it);
            int sb = __shfl(s_l, gbase + it + 1);
            int sc = __shfl(s_l, gbase + it + 2);
            int sd = __shfl(s_l, gbase + it + 3);
            float w0a = __shfl(w0, gbase + it),     w1a = __shfl(w1, gbase + it);
            float w0b = __shfl(w0, gbase + it + 1), w1b = __shfl(w1, gbase + it + 1);
            float w0c = __shfl(w0, gbase + it + 2), w1c = __shfl(w1, gbase + it + 2);
            float w0d = __shfl(w0, gbase + it + 3), w1d = __shfl(w1, gbase + it + 3);
            float wa = head ? w1a : w0a;
            float wb = head ? w1b : w0b;
            float wc = head ? w1c : w0c;
            float wd = head ? w1d : w0d;
            uint4 va = *(const uint4*)&Gh[(size_t)sa * 64 + u4];
            uint4 vb = *(const uint4*)&Gh[(size_t)sb * 64 + u4];
            uint4 vc = *(const uint4*)&Gh[(size_t)sc * 64 + u4];
            uint4 vd = *(const uint4*)&Gh[(size_t)sd * 64 + u4];
            fma_f16x8(A, va, wa);
            fma_f16x8(A, vb, wb);
            fma_f16x8(A, vc, wc);
            fma_f16x8(A, vd, wd);
        }
        for (; it + 1 < cdeg; it += 2) {
            int sa = __shfl(s_l, gbase + it);
            int sb = __shfl(s_l, gbase + it + 1);
            float w0a = __shfl(w0, gbase + it),     w1a = __shfl(w1, gbase + it);
            float w0b = __shfl(w0, gbase + it + 1), w1b = __shfl(w1, gbase + it + 1);
            float wa = head ? w1a : w0a;
            float wb = head ? w1b : w0b;
            uint4 va = *(const uint4*)&Gh[(size_t)sa * 64 + u4];
            uint4 vb = *(const uint4*)&Gh[(size_t)sb * 64 + u4];
            fma_f16x8(A, va, wa);
            fma_f16x8(A, vb, wb);
        }
        if (it < cdeg) {
            int sa = __shfl(s_l, gbase + it);
            float w0a = __shfl(w0, gbase + it), w1a = __shfl(w1, gbase + it);
            float wa = head ? w1a : w0a;
            uint4 va = *(const uint4*)&Gh[(size_t)sa * 64 + u4];
            fma_f16x8(A, va, wa);
        }
    }
    float rh = 0.5f / ((head ? d1 : d0) + 1e-16f);
    #pragma unroll
    for (int j = 0; j < 8; j++) {
        A[j] *= rh;
        A[j] += __shfl_xor(A[j], 8);   // combine the two heads
    }
    if (head == 0) {
        int cb = (lid & 7) * 8;
        const float4 bg0 = *(const float4*)&bgat[cb];
        const float4 bg1 = *(const float4*)&bgat[cb + 4];
        float4 o0; o0.x = A[0] + bg0.x; o0.y = A[1] + bg0.y; o0.z = A[2] + bg0.z; o0.w = A[3] + bg0.w;
        float4 o1; o1.x = A[4] + bg1.x; o1.y = A[5] + bg1.y; o1.z = A[6] + bg1.z; o1.w = A[7] + bg1.w;
        float* op = &OUT[(size_t)node * 64 + cb];
        *(float4*)op = o0;
        *(float4*)(op + 4) = o1;
    }
}

extern "C" void kernel_launch(void* const* d_in, const int* in_sizes, int n_in,
                              void* d_out, int out_size, void* d_ws, size_t ws_size,
                              hipStream_t stream) {
    const float* x   = (const float*)d_in[0];
    const int*   ei  = (const int*)d_in[1];
    const float* ea  = (const float*)d_in[2];
    const int N = in_sizes[0] / 64;
    const int E = in_sizes[1] / 2;
    const int* src = ei;
    const int* dst = ei + E;

    const float* wn[3] = {(const float*)d_in[3],  (const float*)d_in[9],  (const float*)d_in[15]};
    const float* bn[3] = {(const float*)d_in[4],  (const float*)d_in[10], (const float*)d_in[16]};
    const float* we[3] = {(const float*)d_in[5],  (const float*)d_in[11], (const float*)d_in[17]};
    const float* be[3] = {(const float*)d_in[6],  (const float*)d_in[12], (const float*)d_in[18]};
    const float* wc[3] = {(const float*)d_in[7],  (const float*)d_in[13], (const float*)d_in[19]};
    const float* bc[3] = {(const float*)d_in[8],  (const float*)d_in[14], (const float*)d_in[20]};
    const float* wgat    = (const float*)d_in[21];
    const float* att_src = (const float*)d_in[22];
    const float* att_dst = (const float*)d_in[23];
    const float* bgat    = (const float*)d_in[24];

    // workspace carve-up (256B aligned)
    char* ws = (char*)d_ws;
    size_t off = 0;
    auto alloc = [&](size_t bytes) -> void* {
        void* p = ws + off;
        off = (off + bytes + 255) & ~(size_t)255;
        return p;
    };
    int*   row_start = (int*)alloc((size_t)(N + 1) * 4);
    int*   partials  = (int*)alloc(1024 * 4);
    int*   rank      = (int*)alloc((size_t)E * 4);
    int2*  csr_se    = (int2*)alloc((size_t)E * 8);
    float* Wc        = (float*)alloc((size_t)3 * 4480 * 4);   // per layer: W1|W2|cv
    u32*   Wgh       = (u32*)alloc((size_t)4096 * 4);         // Wg fp16 [64][64] u32
    float* B5        = (float*)alloc((size_t)N * 5 * 4);
    u32*   xh        = (u32*)alloc((size_t)N * 64 * 2);       // x fp16 [N][64]
    u32*   bufH0     = (u32*)alloc((size_t)N * 64 * 2);       // h ping (fp16 [N][64])
    u32*   bufH1     = (u32*)alloc((size_t)N * 64 * 2);       // h pong (fp16 [N][64])
    u32*   Gh        = (u32*)alloc((size_t)N * 64 * 4);       // fp16 G [N][128]
    float* asrc      = (float*)alloc((size_t)N * 2 * 4);
    float* adst      = (float*)alloc((size_t)N * 2 * 4);
    float* out = (float*)d_out;

    const int nbN = (N + TPB - 1) / TPB;
    const int nbE = (E + TPB - 1) / TPB;
    const int grpBlocks = (N + 15) / 16;
    const int tiles = (N + 63) / 64;
    const int n8 = N * 8;
    const int nbC = (n8 + TPB - 1) / TPB;
    const int nbZ = (N + 1 + TPB - 1) / TPB;

    // ---- mega-prep: folds + Wg pack + x cvt + row_start zero (ONE launch) --
    CombPtrs p0 = {wn[0], bn[0], we[0], be[0], wc[0], bc[0], Wc};
    CombPtrs p1 = {wn[1], bn[1], we[1], be[1], wc[1], bc[1], Wc + 4480};
    CombPtrs p2 = {wn[2], bn[2], we[2], be[2], wc[2], bc[2], Wc + 2 * 4480};
    k_prep<<<4 + nbC + nbZ, TPB, 0, stream>>>(p0, p1, p2, wgat, Wgh,
                                              (const float4*)x, (uint4*)xh, n8, nbC,
                                              row_start, N + 1);

    // ---- CSR build: hist(+rank), scan1, scan3(self-prefix), scatter ----
    k_hist<<<nbE, TPB, 0, stream>>>(dst, row_start, rank, E);
    k_scan1<<<nbN, TPB, 0, stream>>>(row_start, partials, N);
    k_scan3<<<nbN, TPB, 0, stream>>>(row_start, partials, N, E);
    k_scatter<<<nbE, TPB, 0, stream>>>(src, dst, rank, row_start, csr_se, E);

    // ---- 3 fused edge-conv layers (EC1 also computes B5 from EA) ----
    k_ec_fused<true, true, false, true><<<tiles, TPB, 0, stream>>>(
        xh,    row_start, csr_se, Wc,            B5, ea, bufH0, N,
        nullptr, nullptr, nullptr, nullptr, nullptr, nullptr);
    k_ec_fused<true, true, false, false><<<tiles, TPB, 0, stream>>>(
        bufH0, row_start, csr_se, Wc + 4480,     B5, nullptr, bufH1, N,
        nullptr, nullptr, nullptr, nullptr, nullptr, nullptr);
    // EC3 + GAT GEMM fused: h3 never written to global; Wg fp16 via LDS
    k_ec_fused<true, true, true, false><<<tiles, TPB, 0, stream>>>(
        bufH1, row_start, csr_se, Wc + 2 * 4480, B5, nullptr, nullptr, N,
        Wgh, att_src, att_dst, Gh, asrc, adst);

    // ---- GAT aggregation ----
    k_gat_agg<<<grpBlocks, TPB, 0, stream>>>(Gh, row_start, csr_se, asrc, adst, bgat, out, N);
}